// Round 17
// baseline (51.023 us; speedup 1.0000x reference)
//
#include <hip/hip_runtime.h>
#include <hip/hip_bf16.h>

// LBONorm: fused LayerNorm + low-rank diffusion smoothing.
// rows = B*S = 16384, d = 2048 (fp32), rank = 8.
// Block = 256 thr (4 waves) owns 16 rows; thread t owns cols {4t..4t+3, 1024+4t..+3}.
// R1/R8: launch_bounds cap < demand -> spill. Use (256,2) always.
// R4: DPP wave-reduce: 81.5 -> 57.6. R9: split-phase batching: -> 52.8.
// R12: stage-major fused v_add_f32_dpp (hazard-safe): -> 48.7. R13: -> 48.3.
// R5/R6/R7/R14/R15/R16 (VALU diet, barrier, NT, TLP, pipeline, pk-asm): null.
// R17: monolithic ROWS_PB=16 -- amortize block startup (V wait + vsum + 2
//   barriers ~0.8us) over 2x rows, 32 float4 in flight/thread, phase-1 DPP
//   batch 160 values (max ILP). VGPR ~220 < 256 cap: TLP->ILP trade.
//   If >=47us with clean counters: structural plateau, ROOFLINE next.

constexpr int D       = 2048;
constexpr int RANK    = 8;
constexpr int BLOCK   = 256;
constexpr int ROWS_PB = 16;
constexpr float LN_EPS = 1e-5f;

using f2  = __attribute__((ext_vector_type(2))) float;
using f4v = __attribute__((ext_vector_type(4))) float;

__device__ __forceinline__ f2 f2fma(f2 a, f2 b, f2 c) {
    return __builtin_elementwise_fma(a, b, c);
}

// NT store: no cache allocate (write stream is touch-once).
__device__ __forceinline__ void nt_store4(float* p, float x, float y, float z, float w) {
    f4v v = {x, y, z, w};
    __builtin_nontemporal_store(v, reinterpret_cast<f4v*>(p));
}

// Barrier draining ONLY lgkmcnt (LDS) -- global loads/stores stay in flight.
__device__ __forceinline__ void barrier_lds() {
    asm volatile("s_waitcnt lgkmcnt(0)\n\ts_barrier" ::: "memory");
}

// Ordered horizontal add feeding the DPP stages (asm program order guarantees
// the first DPP read of each value is >= N instructions after its write).
__device__ __forceinline__ float ordadd(float a, float b) {
    float r;
    asm volatile("v_add_f32 %0, %1, %2" : "=v"(r) : "v"(a), "v"(b));
    return r;
}

// One DPP stage applied across an N-element array (stage-major => same-reg
// DPP writes are N apart; hazard needs 2).
#define DPP_STAGE(v, N, MODS)                                                   \
    _Pragma("unroll")                                                           \
    for (int _n = 0; _n < N; ++_n)                                              \
        asm volatile("v_add_f32_dpp %0, %0, %0 " MODS : "+v"(v[_n]));

// Full 64-lane sum of N independent values; totals valid in lane 63.
template<int N>
__device__ __forceinline__ void dpp_sum64_batch(float (&v)[N]) {
    static_assert(N >= 4, "need N>=4 for hazard distance");
    DPP_STAGE(v, N, "row_shr:1 row_mask:0xf bank_mask:0xf bound_ctrl:0")
    DPP_STAGE(v, N, "row_shr:2 row_mask:0xf bank_mask:0xf bound_ctrl:0")
    DPP_STAGE(v, N, "row_shr:4 row_mask:0xf bank_mask:0xf bound_ctrl:0")
    DPP_STAGE(v, N, "row_shr:8 row_mask:0xf bank_mask:0xf bound_ctrl:0")
    DPP_STAGE(v, N, "row_bcast:15 row_mask:0xa bank_mask:0xf bound_ctrl:0")
    DPP_STAGE(v, N, "row_bcast:31 row_mask:0xc bank_mask:0xf bound_ctrl:0")
}

// 4-lane group totals (all 4 lanes get the sum) of N independent values.
template<int N>
__device__ __forceinline__ void qp_sum4_batch(float (&v)[N]) {
    static_assert(N >= 4, "need N>=4 for hazard distance");
    asm volatile("s_nop 1");
    DPP_STAGE(v, N, "quad_perm:[1,0,3,2] row_mask:0xf bank_mask:0xf bound_ctrl:0")
    DPP_STAGE(v, N, "quad_perm:[2,3,0,1] row_mask:0xf bank_mask:0xf bound_ctrl:0")
}

__global__ __launch_bounds__(BLOCK, 2)
void lbonorm_kernel(const float* __restrict__ h,
                    const float* __restrict__ gamma,
                    const float* __restrict__ beta,
                    const float* __restrict__ V,
                    const float* __restrict__ eta_p,
                    float* __restrict__ out,
                    float* __restrict__ e_out)
{
    const int t    = threadIdx.x;
    const int lane = t & 63;
    const int wave = t >> 6;

    const int c0 = t * 4;
    const int c1 = D / 2 + t * 4;

    // red[row][wave][12]: {s, s2, dot0..7, pad, pad}
    __shared__ __align__(16) float red[ROWS_PB][4][12];
    __shared__ __align__(16) float ered[4][ROWS_PB];   // vsum staging + e partials

    const size_t row0 = (size_t)blockIdx.x * ROWS_PB;

    // ---- V / gamma / beta first (setup waits only on these); h after.
    f2 vreg[4][RANK];
    #pragma unroll
    for (int r = 0; r < RANK; ++r) {
        float4 a = *reinterpret_cast<const float4*>(V + (size_t)r * D + c0);
        float4 b = *reinterpret_cast<const float4*>(V + (size_t)r * D + c1);
        vreg[0][r] = f2{a.x, a.y}; vreg[1][r] = f2{a.z, a.w};
        vreg[2][r] = f2{b.x, b.y}; vreg[3][r] = f2{b.z, b.w};
    }
    const float4 g0 = *reinterpret_cast<const float4*>(gamma + c0);
    const float4 g1 = *reinterpret_cast<const float4*>(gamma + c1);
    const float4 bb0 = *reinterpret_cast<const float4*>(beta + c0);
    const float4 bb1 = *reinterpret_cast<const float4*>(beta + c1);
    const f2 gam[4] = {f2{g0.x,g0.y}, f2{g0.z,g0.w}, f2{g1.x,g1.y}, f2{g1.z,g1.w}};
    const f2 bet[4] = {f2{bb0.x,bb0.y}, f2{bb0.z,bb0.w}, f2{bb1.x,bb1.y}, f2{bb1.z,bb1.w}};
    const float eta = fminf(fmaxf(eta_p[0], 0.0f), 0.5f);

    // ---- all 16 rows' h loads issued after V (512 B/lane in flight)
    float4 hx[ROWS_PB][2];
    #pragma unroll
    for (int r = 0; r < ROWS_PB; ++r) {
        hx[r][0] = *reinterpret_cast<const float4*>(h + (row0 + r) * (size_t)D + c0);
        hx[r][1] = *reinterpret_cast<const float4*>(h + (row0 + r) * (size_t)D + c1);
    }

    // ---- per-rank column sums of V (staged in ered; one barrier)
    float vsum[RANK];
    {
        float vs[RANK];
        #pragma unroll
        for (int r = 0; r < RANK; ++r) {
            f2 v = (vreg[0][r] + vreg[1][r]) + (vreg[2][r] + vreg[3][r]);
            vs[r] = ordadd(v.x, v.y);
        }
        dpp_sum64_batch(vs);
        if (lane == 63) {
            float4* dst = reinterpret_cast<float4*>(&ered[wave][0]);
            dst[0] = make_float4(vs[0], vs[1], vs[2], vs[3]);
            dst[1] = make_float4(vs[4], vs[5], vs[6], vs[7]);
        }
        barrier_lds();
        const float4* src = reinterpret_cast<const float4*>(&ered[lane & 3][0]);
        const float4 qa = src[0], qb = src[1];
        float qv[8] = {qa.x, qa.y, qa.z, qa.w, qb.x, qb.y, qb.z, qb.w};
        qp_sum4_batch(qv);
        #pragma unroll
        for (int k = 0; k < RANK; ++k) vsum[k] = qv[k];
        barrier_lds();   // protect ered before phase-2 reuse
    }

    // ==== PHASE 1: all 16 rows' partials + batched DPP reduce (160 values
    // stage-major: DPP pipeline at full duty), no inner barrier.
    #pragma unroll
    for (int r = 0; r < ROWS_PB; ++r) {
        const f2 h2[4] = {f2{hx[r][0].x, hx[r][0].y}, f2{hx[r][0].z, hx[r][0].w},
                          f2{hx[r][1].x, hx[r][1].y}, f2{hx[r][1].z, hx[r][1].w}};
        float vals[10];
        {
            f2 s  = (h2[0] + h2[1]) + (h2[2] + h2[3]);
            f2 s2 = f2fma(h2[0], h2[0], f2fma(h2[1], h2[1],
                    f2fma(h2[2], h2[2], h2[3] * h2[3])));
            vals[0] = ordadd(s.x, s.y);
            vals[1] = ordadd(s2.x, s2.y);
            #pragma unroll
            for (int k = 0; k < RANK; ++k) {
                f2 d = f2fma(h2[0], vreg[0][k], f2fma(h2[1], vreg[1][k],
                       f2fma(h2[2], vreg[2][k], h2[3] * vreg[3][k])));
                vals[2 + k] = ordadd(d.x, d.y);
            }
        }
        dpp_sum64_batch(vals);

        if (lane == 63) {
            float4* dst = reinterpret_cast<float4*>(&red[r][wave][0]);
            dst[0] = make_float4(vals[0], vals[1], vals[2], vals[3]);
            dst[1] = make_float4(vals[4], vals[5], vals[6], vals[7]);
            dst[2] = make_float4(vals[8], vals[9], 0.f, 0.f);
        }
    }

    barrier_lds();   // THE barrier: all rows' partials visible

    // ==== PHASE 2: all 16 rows' combine + epilogue; e partials deferred
    float er[ROWS_PB];
    #pragma unroll
    for (int r = 0; r < ROWS_PB; ++r) {
        const float4* src = reinterpret_cast<const float4*>(&red[r][lane & 3][0]);
        const float4 q0 = src[0], q1 = src[1], q2 = src[2];
        float qv[10] = {q0.x, q0.y, q0.z, q0.w, q1.x, q1.y, q1.z, q1.w, q2.x, q2.y};
        qp_sum4_batch(qv);

        const float mu  = qv[0] * (1.0f / D);
        const float var = fmaxf(qv[1] * (1.0f / D) - mu * mu, 0.0f);
        const float inv = rsqrtf(var + LN_EPS);
        f2 c2[RANK];
        #pragma unroll
        for (int k = 0; k < RANK; ++k) {
            const float c = inv * (qv[2 + k] - mu * vsum[k]);
            c2[k] = f2{c, c};
        }

        const f2 h2[4] = {f2{hx[r][0].x, hx[r][0].y}, f2{hx[r][0].z, hx[r][0].w},
                          f2{hx[r][1].x, hx[r][1].y}, f2{hx[r][1].z, hx[r][1].w}};
        const f2 inv2  = f2{inv, inv};
        const f2 nmi2  = f2{-mu * inv, -mu * inv};
        const f2 neta2 = f2{-eta, -eta};
        f2 e2 = f2{0.f, 0.f};
        f2 ov[4];
        #pragma unroll
        for (int k = 0; k < 4; ++k) {
            const f2 hh = f2fma(h2[k], inv2, nmi2);
            f2 pr = c2[0] * vreg[k][0];
            #pragma unroll
            for (int q = 1; q < RANK; ++q) pr = f2fma(c2[q], vreg[k][q], pr);
            const f2 dl = hh - pr;
            e2 = f2fma(dl, dl, e2);
            const f2 sm = f2fma(neta2, dl, hh);
            ov[k] = f2fma(sm, gam[k], bet[k]);
        }

        float* orow = out + (row0 + r) * (size_t)D;
        nt_store4(orow + c0, ov[0].x, ov[0].y, ov[1].x, ov[1].y);
        nt_store4(orow + c1, ov[2].x, ov[2].y, ov[3].x, ov[3].y);

        er[r] = ordadd(e2.x, e2.y);
    }

    // ---- batched e_curv reduce for all 16 rows (reuses ered; fenced)
    dpp_sum64_batch(er);
    if (lane == 63) {
        float4* dst = reinterpret_cast<float4*>(&ered[wave][0]);
        dst[0] = make_float4(er[0],  er[1],  er[2],  er[3]);
        dst[1] = make_float4(er[4],  er[5],  er[6],  er[7]);
        dst[2] = make_float4(er[8],  er[9],  er[10], er[11]);
        dst[3] = make_float4(er[12], er[13], er[14], er[15]);
    }
    barrier_lds();
    if (t < ROWS_PB) {
        const float e = (ered[0][t] + ered[1][t]) + (ered[2][t] + ered[3][t]);
        e_out[row0 + t] = e;
    }
}

extern "C" void kernel_launch(void* const* d_in, const int* in_sizes, int n_in,
                              void* d_out, int out_size, void* d_ws, size_t ws_size,
                              hipStream_t stream) {
    const float* h     = (const float*)d_in[0];
    const float* gamma = (const float*)d_in[1];
    const float* beta  = (const float*)d_in[2];
    const float* V     = (const float*)d_in[3];
    const float* eta   = (const float*)d_in[4];
    float* out = (float*)d_out;

    const int d = in_sizes[1];                       // 2048
    const long long rows = in_sizes[0] / d;          // 16384
    float* e_out = out + (size_t)rows * d;

    dim3 grid((unsigned)(rows / ROWS_PB));           // 1024
    lbonorm_kernel<<<grid, BLOCK, 0, stream>>>(h, gamma, beta, V, eta, out, e_out);
}

// Round 18
// 48.212 us; speedup vs baseline: 1.0583x; 1.0583x over previous
//
#include <hip/hip_runtime.h>
#include <hip/hip_bf16.h>

// LBONorm: fused LayerNorm + low-rank diffusion smoothing.
// rows = B*S = 16384, d = 2048 (fp32), rank = 8.
// Block = 256 thr (4 waves) owns 8 rows; thread t owns cols {4t..4t+3, 1024+4t..+3}.
// BEST KNOWN CONFIG (R13, 48.3 us) -- reverted after R14-R17 probes all null/regress:
// R1/R8: launch_bounds cap < demand -> spill. Use (256,2) always.
// R4: DPP wave-reduce: 81.5 -> 57.6. R9: split-phase batching: -> 52.8.
// R10/R11: back-to-back inline-asm DPP violated the 2-wait-state VALU->DPP
//   hazard. R12: stage-major batched DPP (same-reg writes >= N apart): -> 48.7.
// R13: V-before-h load order: 48.3 (best).
// R14 (2x blocks) / R15 (chunk pipeline) / R16 (pk asm) / R17 (ROWS_PB=16,
//   compiler re-scheduled loads at VGPR=128): all null or regress ->
//   structural plateau: per-row 64-lane reduce -> LDS round-trip chain
//   latency at ~65% of mixed-stream HBM BW. 197MB/48.3us = 4.1 TB/s.

constexpr int D       = 2048;
constexpr int RANK    = 8;
constexpr int BLOCK   = 256;
constexpr int ROWS_PB = 8;
constexpr float LN_EPS = 1e-5f;

using f2  = __attribute__((ext_vector_type(2))) float;
using f4v = __attribute__((ext_vector_type(4))) float;

__device__ __forceinline__ f2 f2fma(f2 a, f2 b, f2 c) {
    return __builtin_elementwise_fma(a, b, c);
}

// NT store: no cache allocate (write stream is touch-once).
__device__ __forceinline__ void nt_store4(float* p, float x, float y, float z, float w) {
    f4v v = {x, y, z, w};
    __builtin_nontemporal_store(v, reinterpret_cast<f4v*>(p));
}

// Barrier draining ONLY lgkmcnt (LDS) -- global loads/stores stay in flight.
__device__ __forceinline__ void barrier_lds() {
    asm volatile("s_waitcnt lgkmcnt(0)\n\ts_barrier" ::: "memory");
}

// Ordered horizontal add feeding the DPP stages (asm program order guarantees
// the first DPP read of each value is >= N instructions after its write).
__device__ __forceinline__ float ordadd(float a, float b) {
    float r;
    asm volatile("v_add_f32 %0, %1, %2" : "=v"(r) : "v"(a), "v"(b));
    return r;
}

// One DPP stage applied across an N-element array (stage-major => same-reg
// DPP writes are N apart; hazard needs 2).
#define DPP_STAGE(v, N, MODS)                                                   \
    _Pragma("unroll")                                                           \
    for (int _n = 0; _n < N; ++_n)                                              \
        asm volatile("v_add_f32_dpp %0, %0, %0 " MODS : "+v"(v[_n]));

// Full 64-lane sum of N independent values; totals valid in lane 63.
template<int N>
__device__ __forceinline__ void dpp_sum64_batch(float (&v)[N]) {
    static_assert(N >= 4, "need N>=4 for hazard distance");
    DPP_STAGE(v, N, "row_shr:1 row_mask:0xf bank_mask:0xf bound_ctrl:0")
    DPP_STAGE(v, N, "row_shr:2 row_mask:0xf bank_mask:0xf bound_ctrl:0")
    DPP_STAGE(v, N, "row_shr:4 row_mask:0xf bank_mask:0xf bound_ctrl:0")
    DPP_STAGE(v, N, "row_shr:8 row_mask:0xf bank_mask:0xf bound_ctrl:0")
    DPP_STAGE(v, N, "row_bcast:15 row_mask:0xa bank_mask:0xf bound_ctrl:0")
    DPP_STAGE(v, N, "row_bcast:31 row_mask:0xc bank_mask:0xf bound_ctrl:0")
}

// 4-lane group totals (all 4 lanes get the sum) of N independent values.
template<int N>
__device__ __forceinline__ void qp_sum4_batch(float (&v)[N]) {
    static_assert(N >= 4, "need N>=4 for hazard distance");
    asm volatile("s_nop 1");
    DPP_STAGE(v, N, "quad_perm:[1,0,3,2] row_mask:0xf bank_mask:0xf bound_ctrl:0")
    DPP_STAGE(v, N, "quad_perm:[2,3,0,1] row_mask:0xf bank_mask:0xf bound_ctrl:0")
}

__global__ __launch_bounds__(BLOCK, 2)
void lbonorm_kernel(const float* __restrict__ h,
                    const float* __restrict__ gamma,
                    const float* __restrict__ beta,
                    const float* __restrict__ V,
                    const float* __restrict__ eta_p,
                    float* __restrict__ out,
                    float* __restrict__ e_out)
{
    const int t    = threadIdx.x;
    const int lane = t & 63;
    const int wave = t >> 6;

    const int c0 = t * 4;
    const int c1 = D / 2 + t * 4;

    // red[row][wave][12]: {s, s2, dot0..7, pad, pad}
    __shared__ __align__(16) float red[ROWS_PB][4][12];
    __shared__ __align__(16) float ered[4][ROWS_PB];   // vsum staging + e partials

    const size_t row0 = (size_t)blockIdx.x * ROWS_PB;

    // ---- V / gamma / beta loads FIRST: the setup phase waits only on these
    // (vmcnt is in-order; h issued after => h stays in flight through setup).
    f2 vreg[4][RANK];
    #pragma unroll
    for (int r = 0; r < RANK; ++r) {
        float4 a = *reinterpret_cast<const float4*>(V + (size_t)r * D + c0);
        float4 b = *reinterpret_cast<const float4*>(V + (size_t)r * D + c1);
        vreg[0][r] = f2{a.x, a.y}; vreg[1][r] = f2{a.z, a.w};
        vreg[2][r] = f2{b.x, b.y}; vreg[3][r] = f2{b.z, b.w};
    }
    const float4 g0 = *reinterpret_cast<const float4*>(gamma + c0);
    const float4 g1 = *reinterpret_cast<const float4*>(gamma + c1);
    const float4 bb0 = *reinterpret_cast<const float4*>(beta + c0);
    const float4 bb1 = *reinterpret_cast<const float4*>(beta + c1);
    const f2 gam[4] = {f2{g0.x,g0.y}, f2{g0.z,g0.w}, f2{g1.x,g1.y}, f2{g1.z,g1.w}};
    const f2 bet[4] = {f2{bb0.x,bb0.y}, f2{bb0.z,bb0.w}, f2{bb1.x,bb1.y}, f2{bb1.z,bb1.w}};
    const float eta = fminf(fmaxf(eta_p[0], 0.0f), 0.5f);

    // ---- ALL 8 rows' h loads issued AFTER V (stream in under setup+phase1)
    float4 hx[ROWS_PB][2];
    #pragma unroll
    for (int r = 0; r < ROWS_PB; ++r) {
        hx[r][0] = *reinterpret_cast<const float4*>(h + (row0 + r) * (size_t)D + c0);
        hx[r][1] = *reinterpret_cast<const float4*>(h + (row0 + r) * (size_t)D + c1);
    }

    // ---- per-rank column sums of V
    float vsum[RANK];
    {
        float vs[RANK];
        #pragma unroll
        for (int r = 0; r < RANK; ++r) {
            f2 v = (vreg[0][r] + vreg[1][r]) + (vreg[2][r] + vreg[3][r]);
            vs[r] = ordadd(v.x, v.y);
        }
        dpp_sum64_batch(vs);
        if (lane == 63) {
            float4* dst = reinterpret_cast<float4*>(&red[0][wave][0]);
            dst[0] = make_float4(vs[0], vs[1], vs[2], vs[3]);
            dst[1] = make_float4(vs[4], vs[5], vs[6], vs[7]);
        }
        barrier_lds();
        const float4* src = reinterpret_cast<const float4*>(&red[0][lane & 3][0]);
        const float4 qa = src[0], qb = src[1];
        float qv[8] = {qa.x, qa.y, qa.z, qa.w, qb.x, qb.y, qb.z, qb.w};
        qp_sum4_batch(qv);
        #pragma unroll
        for (int k = 0; k < RANK; ++k) vsum[k] = qv[k];
        barrier_lds();   // protect red[0] before phase 1 overwrites it
    }

    // ==== PHASE 1: all 8 rows' partials + batched DPP reduce, no inner barrier
    #pragma unroll
    for (int r = 0; r < ROWS_PB; ++r) {
        const f2 h2[4] = {f2{hx[r][0].x, hx[r][0].y}, f2{hx[r][0].z, hx[r][0].w},
                          f2{hx[r][1].x, hx[r][1].y}, f2{hx[r][1].z, hx[r][1].w}};
        float vals[10];
        {
            f2 s  = (h2[0] + h2[1]) + (h2[2] + h2[3]);
            f2 s2 = f2fma(h2[0], h2[0], f2fma(h2[1], h2[1],
                    f2fma(h2[2], h2[2], h2[3] * h2[3])));
            vals[0] = ordadd(s.x, s.y);
            vals[1] = ordadd(s2.x, s2.y);
            #pragma unroll
            for (int k = 0; k < RANK; ++k) {
                f2 d = f2fma(h2[0], vreg[0][k], f2fma(h2[1], vreg[1][k],
                       f2fma(h2[2], vreg[2][k], h2[3] * vreg[3][k])));
                vals[2 + k] = ordadd(d.x, d.y);
            }
        }
        dpp_sum64_batch(vals);

        if (lane == 63) {
            float4* dst = reinterpret_cast<float4*>(&red[r][wave][0]);
            dst[0] = make_float4(vals[0], vals[1], vals[2], vals[3]);
            dst[1] = make_float4(vals[4], vals[5], vals[6], vals[7]);
            dst[2] = make_float4(vals[8], vals[9], 0.f, 0.f);
        }
    }

    barrier_lds();   // THE barrier: all rows' partials visible

    // ==== PHASE 2: all 8 rows' combine + epilogue; e partials deferred
    float er[ROWS_PB];
    #pragma unroll
    for (int r = 0; r < ROWS_PB; ++r) {
        const float4* src = reinterpret_cast<const float4*>(&red[r][lane & 3][0]);
        const float4 q0 = src[0], q1 = src[1], q2 = src[2];
        float qv[10] = {q0.x, q0.y, q0.z, q0.w, q1.x, q1.y, q1.z, q1.w, q2.x, q2.y};
        qp_sum4_batch(qv);

        const float mu  = qv[0] * (1.0f / D);
        const float var = fmaxf(qv[1] * (1.0f / D) - mu * mu, 0.0f);
        const float inv = rsqrtf(var + LN_EPS);
        f2 c2[RANK];
        #pragma unroll
        for (int k = 0; k < RANK; ++k) {
            const float c = inv * (qv[2 + k] - mu * vsum[k]);
            c2[k] = f2{c, c};
        }

        const f2 h2[4] = {f2{hx[r][0].x, hx[r][0].y}, f2{hx[r][0].z, hx[r][0].w},
                          f2{hx[r][1].x, hx[r][1].y}, f2{hx[r][1].z, hx[r][1].w}};
        const f2 inv2  = f2{inv, inv};
        const f2 nmi2  = f2{-mu * inv, -mu * inv};
        const f2 neta2 = f2{-eta, -eta};
        f2 e2 = f2{0.f, 0.f};
        f2 ov[4];
        #pragma unroll
        for (int k = 0; k < 4; ++k) {
            const f2 hh = f2fma(h2[k], inv2, nmi2);
            f2 pr = c2[0] * vreg[k][0];
            #pragma unroll
            for (int q = 1; q < RANK; ++q) pr = f2fma(c2[q], vreg[k][q], pr);
            const f2 dl = hh - pr;
            e2 = f2fma(dl, dl, e2);
            const f2 sm = f2fma(neta2, dl, hh);
            ov[k] = f2fma(sm, gam[k], bet[k]);
        }

        float* orow = out + (row0 + r) * (size_t)D;
        nt_store4(orow + c0, ov[0].x, ov[0].y, ov[1].x, ov[1].y);
        nt_store4(orow + c1, ov[2].x, ov[2].y, ov[3].x, ov[3].y);

        er[r] = ordadd(e2.x, e2.y);
    }

    // ---- batched e_curv reduce for all 8 rows (dedicated LDS, no slot race)
    dpp_sum64_batch(er);
    if (lane == 63) {
        float4* dst = reinterpret_cast<float4*>(&ered[wave][0]);
        dst[0] = make_float4(er[0], er[1], er[2], er[3]);
        dst[1] = make_float4(er[4], er[5], er[6], er[7]);
    }
    barrier_lds();
    if (t < ROWS_PB) {
        const float e = (ered[0][t] + ered[1][t]) + (ered[2][t] + ered[3][t]);
        e_out[row0 + t] = e;
    }
}

extern "C" void kernel_launch(void* const* d_in, const int* in_sizes, int n_in,
                              void* d_out, int out_size, void* d_ws, size_t ws_size,
                              hipStream_t stream) {
    const float* h     = (const float*)d_in[0];
    const float* gamma = (const float*)d_in[1];
    const float* beta  = (const float*)d_in[2];
    const float* V     = (const float*)d_in[3];
    const float* eta   = (const float*)d_in[4];
    float* out = (float*)d_out;

    const int d = in_sizes[1];                       // 2048
    const long long rows = in_sizes[0] / d;          // 16384
    float* e_out = out + (size_t)rows * d;

    dim3 grid((unsigned)(rows / ROWS_PB));
    lbonorm_kernel<<<grid, BLOCK, 0, stream>>>(h, gamma, beta, V, eta, out, e_out);
}